// Round 9
// baseline (194.102 us; speedup 1.0000x reference)
//
#include <hip/hip_runtime.h>

#define BB 16
#define CC 256
#define NN 1024

typedef _Float16 f16;
typedef __attribute__((ext_vector_type(8))) _Float16 half8;   // MFMA A/B frag (4 VGPRs)
typedef __attribute__((ext_vector_type(4))) float f32x4;      // MFMA C/D frag

__device__ __forceinline__ half8 ldg8(const f16* p) {
  return *reinterpret_cast<const half8*>(p);
}

// async global->LDS, 16B per lane; lds base must be wave-uniform (HW adds lane*16)
__device__ __forceinline__ void gll16(const f16* g, f16* l) {
  __builtin_amdgcn_global_load_lds((const __attribute__((address_space(1))) void*)g,
                                   (__attribute__((address_space(3))) void*)l, 16, 0, 0);
}

#define VMCNT(n) asm volatile("s_waitcnt vmcnt(" #n ")" ::: "memory")
#define BAR() __builtin_amdgcn_s_barrier()

// stage one contiguous 32 KB chunk (16384 f16) with 512 threads (8 waves): 4 issues/thread.
__device__ __forceinline__ void stage32k8(const f16* __restrict__ g, f16* l, int wave, int lane) {
#pragma unroll
  for (int k = 0; k < 4; ++k) {
    int ob = k * 4096 + wave * 512;      // 8 waves x 512 = 4096 per k
    gll16(g + ob + lane * 8, l + ob);
  }
}

// ---------------- weight pack: W fp32 [ci][co] -> frag-packed f16 wp[(ct*8+kc)*512 + lane*8] ----
struct WP5 {
  const float* s[5];
  f16* d[5];
};

__global__ void __launch_bounds__(256) k_packW(WP5 p) {
  __shared__ float ws[256][17];
  int m = blockIdx.y, ct = blockIdx.x;
  const float* W = p.s[m];
  f16* wp = p.d[m];
  int tid = threadIdx.x;
  int col = tid & 15, cig = tid >> 4;
#pragma unroll
  for (int pg = 0; pg < 16; ++pg) {
    int ci = pg * 16 + cig;
    ws[ci][col] = W[(size_t)ci * 256 + ct * 16 + col];
  }
  __syncthreads();
  int lane = tid & 63, wave = tid >> 6;
  int row16 = lane & 15, quad = lane >> 4;
#pragma unroll
  for (int kk = 0; kk < 2; ++kk) {
    int kc = wave * 2 + kk;
    half8 o;
#pragma unroll
    for (int j = 0; j < 8; ++j) o[j] = (f16)ws[kc * 32 + quad * 8 + j][row16];
    *reinterpret_cast<half8*>(wp + ((size_t)ct * 8 + kc) * 512 + lane * 8) = o;
  }
}

// ---------------- QKV (z-merged; + (256,2) so the allocator budgets for the TRUE
// residency of 2 blocks/CU -> 256-VGPR budget -> more weight loads in flight) ----------------
struct QkvSmem {
  union {
    struct { f16 hi[32][264]; f16 lo[32][264]; } ts;
    f16 ex[2][16][264];
    f16 exv[256][40];
  };
};

__global__ void __launch_bounds__(256, 2) k_qkv(const float* __restrict__ x,
    const f16* __restrict__ wqp, const f16* __restrict__ wkp, const f16* __restrict__ wvp,
    const float* __restrict__ bq, const float* __restrict__ bk, const float* __restrict__ bv,
    f16* __restrict__ qp, f16* __restrict__ kp, f16* __restrict__ vp, int b_base) {
  __shared__ QkvSmem sm;
  int bl = blockIdx.x, bg = b_base + bl, n0 = blockIdx.y * 32;
  int tid = threadIdx.x, wave = tid >> 6, lane = tid & 63;
  int row16 = lane & 15, quad = lane >> 4;
  int g = wave >> 1, h = wave & 1;

#pragma unroll
  for (int e = tid; e < 2048; e += 256) {
    int c = e >> 3, n4 = (e & 7) << 2;
    float4 u = *reinterpret_cast<const float4*>(x + (size_t)(bg * CC + c) * NN + n0 + n4);
    float uv[4] = {u.x, u.y, u.z, u.w};
#pragma unroll
    for (int i = 0; i < 4; ++i) {
      f16 hh = (f16)uv[i];
      sm.ts.hi[n4 + i][c] = hh;
      sm.ts.lo[n4 + i][c] = (f16)(uv[i] - (float)hh);
    }
  }
  __syncthreads();

  half8 ah[8], al[8];
#pragma unroll
  for (int kc = 0; kc < 8; ++kc) {
    ah[kc] = *reinterpret_cast<const half8*>(&sm.ts.hi[g * 16 + row16][kc * 32 + quad * 8]);
    al[kc] = *reinterpret_cast<const half8*>(&sm.ts.lo[g * 16 + row16][kc * 32 + quad * 8]);
  }
  __syncthreads();

  const f16* WTs[2]    = {wqp, wkp};
  const float* biases[2] = {bq, bk};
  f16* outs[2]         = {qp, kp};
#pragma unroll
  for (int z = 0; z < 2; ++z) {
    const f16* WT = WTs[z];
    const float* bias = biases[z];
    f16* outp = outs[z];
#pragma unroll
    for (int cp = 0; cp < 2; ++cp) {
      f32x4 acch[4], accl[4];
#pragma unroll
      for (int u = 0; u < 4; ++u) { acch[u] = {0.f,0.f,0.f,0.f}; accl[u] = {0.f,0.f,0.f,0.f}; }
#pragma unroll
      for (int kc = 0; kc < 8; ++kc) {
#pragma unroll
        for (int u = 0; u < 4; ++u) {
          int ct = h * 8 + cp * 4 + u;
          half8 b = ldg8(WT + ((size_t)ct * 8 + kc) * 512 + lane * 8);
          acch[u] = __builtin_amdgcn_mfma_f32_16x16x32_f16(ah[kc], b, acch[u], 0, 0, 0);
          accl[u] = __builtin_amdgcn_mfma_f32_16x16x32_f16(al[kc], b, accl[u], 0, 0, 0);
        }
      }
#pragma unroll
      for (int u = 0; u < 4; ++u) {
        int ct = h * 8 + cp * 4 + u;
        int co = ct * 16 + row16;
        float bb = bias[co];
#pragma unroll
        for (int r = 0; r < 4; ++r)
          sm.ex[g][quad * 4 + r][co] = (f16)(acch[u][r] + accl[u][r] + bb);
      }
    }
    const f16* exr = &sm.ex[g][row16][0];
    size_t fb = ((size_t)bl * 64 + (n0 >> 4) + g) * 8;
#pragma unroll
    for (int k = 0; k < 4; ++k) {
      int kc = h * 4 + k;
      half8 hv = *reinterpret_cast<const half8*>(exr + kc * 32 + quad * 8);
      *reinterpret_cast<half8*>(outp + (fb + kc) * 512 + lane * 8) = hv;
    }
  }
  __syncthreads();

#pragma unroll
  for (int cp = 0; cp < 2; ++cp) {
    f32x4 acch[4], accl[4];
#pragma unroll
    for (int u = 0; u < 4; ++u) { acch[u] = {0.f,0.f,0.f,0.f}; accl[u] = {0.f,0.f,0.f,0.f}; }
#pragma unroll
    for (int kc = 0; kc < 8; ++kc) {
#pragma unroll
      for (int u = 0; u < 4; ++u) {
        int ct = h * 8 + cp * 4 + u;
        half8 b = ldg8(wvp + ((size_t)ct * 8 + kc) * 512 + lane * 8);
        acch[u] = __builtin_amdgcn_mfma_f32_16x16x32_f16(ah[kc], b, acch[u], 0, 0, 0);
        accl[u] = __builtin_amdgcn_mfma_f32_16x16x32_f16(al[kc], b, accl[u], 0, 0, 0);
      }
    }
#pragma unroll
    for (int u = 0; u < 4; ++u) {
      int ct = h * 8 + cp * 4 + u;
      int co = ct * 16 + row16;
      float bb = bv[co];
#pragma unroll
      for (int r = 0; r < 4; ++r)
        sm.exv[co][g * 16 + quad * 4 + r] = (f16)(acch[u][r] + accl[u][r] + bb);
    }
  }
  __syncthreads();
  size_t vb = ((size_t)bl * 32 + blockIdx.y) * 16;
#pragma unroll
  for (int f = 0; f < 4; ++f) {
    int ct = wave * 4 + f;
    half8 o = *reinterpret_cast<const half8*>(&sm.exv[ct * 16 + row16][quad * 8]);
    *reinterpret_cast<half8*>(vp + (vb + ct) * 512 + lane * 8) = o;
  }
}

// ---------------- fused flash attention + MLP(SiLU) + LayerNorm ----------------
// R9: DOUBLE-BUFFERED LDS, 1 barrier + 1 vmcnt PER ITERATION.
// R8 post-mortem: 2-blocks/CU never happened — grid (16,16)=256 blocks on 256 CUs is
// 1 block/CU BY CONSTRUCTION. And 16 its x (4 bar + 2 vmcnt) cost ~11 us vs R4
// (calibration: ~0.22 us/sync-event). So: keep 8 waves (512 thr, (512,2) -> 128 VGPR,
// the only proven-good allocator config), double-buffer the 64-i Q/V chunks (128 KB),
// stage chunk it+1 at iteration START into buf[cur^1] (whole iteration to land), compute
// entirely from buf[cur] (intra-wave, sync-free), then ONE vmcnt(0)+barrier at the end.
// Sync events: 96 -> 32.
struct AttnSmem {
  union {
    struct {
      f16 QB[2][64 * 256];     // 2 x 32 KB: packed q frags, double-buffered 64-i chunks
      f16 VB[2][64 * 256];     // 2 x 32 KB: packed vT frags
    } s;
    struct {
      float Ocmb[4][16][260];  // 66.6 KB: pairwise O-combine (f32); later aliased as h
      f16 ex[4][16][264];      // 33 KB: normalized att
    } e;
  } u;                      // 131072 B
  f16 P[8][16][40];         // per-wave P round-trip (C->A layout)  10240 B
  float ml[8][2][16];       // per-wave {m, l} per j-row             1024 B
  float lnbuf[8][2][16];    // per-wave LN partials {sum, ssq}       1024 B
};                          // total 143360 B (1 block/CU)

__global__ void __launch_bounds__(512, 2) k_attn_mlp(
    const f16* __restrict__ qp, const f16* __restrict__ kp, const f16* __restrict__ vp,
    const f16* __restrict__ w1p, const float* __restrict__ b1,
    const f16* __restrict__ w2p, const float* __restrict__ b2,
    const float* __restrict__ gamma, const float* __restrict__ beta,
    float* __restrict__ out, int b_base) {
  __shared__ AttnSmem sm;
  int bl = blockIdx.x, bg = b_base + bl;
  int j0 = blockIdx.y * 64;
  int tid = threadIdx.x, wave = tid >> 6, lane = tid & 63;
  int row16 = lane & 15, quad = lane >> 4;
  int jt_l = wave & 3, p = wave >> 2;        // j-tile within block, i-parity (0..1)
  int jw = j0 + jt_l * 16;

  // A-frags: k rows of this wave's j-tile (parity partner loads the same rows; L2-hot)
  const f16* kbase = kp + (size_t)bl * NN * CC;
  int jt = (j0 >> 4) + jt_l;
  half8 kf[8];
#pragma unroll
  for (int kc = 0; kc < 8; ++kc)
    kf[kc] = ldg8(kbase + ((size_t)jt * 8 + kc) * 512 + lane * 8);

  const f16* qbase = qp + (size_t)bl * NN * CC;
  const f16* vbase = vp + (size_t)bl * CC * NN;

  // prologue: stage chunk 0 into buffer 0; drain everything (kf included)
  stage32k8(qbase, sm.u.s.QB[0], wave, lane);
  stage32k8(vbase, sm.u.s.VB[0], wave, lane);
  VMCNT(0);
  BAR();

  f32x4 O[16];
#pragma unroll
  for (int ct = 0; ct < 16; ++ct) O[ct] = {0.f, 0.f, 0.f, 0.f};
  float m_run[4], l_lane[4];
#pragma unroll
  for (int r = 0; r < 4; ++r) { m_run[r] = -1e30f; l_lane[r] = 0.f; }

  int cur = 0;
  for (int it = 0; it < 16; ++it) {
    const f16* QBp = &sm.u.s.QB[cur][p * 8192];   // parity's 32 rows = 16 frags
    const f16* VBp = &sm.u.s.VB[cur][p * 8192];

    // issue next-chunk staging into the other buffer — a full iteration to land.
    // safe: buf[cur^1] reads completed before the PREVIOUS end-of-iteration barrier.
    stage32k8(qbase + (size_t)((it + 1) & 15) * 16384, sm.u.s.QB[cur ^ 1], wave, lane);
    stage32k8(vbase + (size_t)((it + 1) & 15) * 16384, sm.u.s.VB[cur ^ 1], wave, lane);

    // ---- QK: scores S[16 j][32 i] from LDS, 2 parallel MFMA chains ----
    f32x4 s[2];
#pragma unroll
    for (int f = 0; f < 2; ++f) s[f] = {0.f, 0.f, 0.f, 0.f};
#pragma unroll
    for (int kc = 0; kc < 8; ++kc) {
#pragma unroll
      for (int f = 0; f < 2; ++f) {
        half8 b = *reinterpret_cast<const half8*>(&QBp[(f * 8 + kc) * 512 + lane * 8]);
        s[f] = __builtin_amdgcn_mfma_f32_16x16x32_f16(kf[kc], b, s[f], 0, 0, 0);
      }
    }

    // ---- softmax per j-row over this wave's 32 i (all intra-wave) ----
    float alpha[4];
#pragma unroll
    for (int r = 0; r < 4; ++r) {
      float mx = fmaxf(s[0][r], s[1][r]);
#pragma unroll
      for (int off = 1; off < 16; off <<= 1) mx = fmaxf(mx, __shfl_xor(mx, off, 64));
      float mnew = fmaxf(m_run[r], mx);
      alpha[r] = __expf(m_run[r] - mnew);
      m_run[r] = mnew;
      float ps = 0.f;
#pragma unroll
      for (int f = 0; f < 2; ++f) {
        float pv = __expf(s[f][r] - mnew);
        ps += pv;
        sm.P[wave][quad * 4 + r][f * 16 + row16] = (f16)pv;
      }
      l_lane[r] = l_lane[r] * alpha[r] + ps;
    }
#pragma unroll
    for (int ct = 0; ct < 16; ++ct)
#pragma unroll
      for (int r = 0; r < 4; ++r) O[ct][r] *= alpha[r];

    // ---- PV: one 32-i chunk; P same-wave LDS round-trip, vT frags from LDS ----
    {
      half8 pf = *reinterpret_cast<const half8*>(&sm.P[wave][row16][quad * 8]);
#pragma unroll
      for (int ct = 0; ct < 16; ++ct) {
        half8 vf = *reinterpret_cast<const half8*>(&VBp[ct * 512 + lane * 8]);
        O[ct] = __builtin_amdgcn_mfma_f32_16x16x32_f16(pf, vf, O[ct], 0, 0, 0);
      }
    }

    VMCNT(0);   // next chunk landed (it had the whole iteration to fly)
    BAR();      // all waves done reading buf[cur]; staged data visible
    cur ^= 1;
  }

  // ---- pairwise (m, l, O) combine across parity waves ----
#pragma unroll
  for (int r = 0; r < 4; ++r) {
#pragma unroll
    for (int off = 1; off < 16; off <<= 1) l_lane[r] += __shfl_xor(l_lane[r], off, 64);
  }
  if (row16 == 0) {
#pragma unroll
    for (int r = 0; r < 4; ++r) {
      sm.ml[wave][0][quad * 4 + r] = m_run[r];
      sm.ml[wave][1][quad * 4 + r] = l_lane[r];
    }
  }
  BAR();

  int partner = wave ^ 4;
  float aS[4], invL[4];
#pragma unroll
  for (int r = 0; r < 4; ++r) {
    int j = quad * 4 + r;
    float ma = m_run[r], mb = sm.ml[partner][0][j];
    float M = fmaxf(ma, mb);
    float L = l_lane[r] * __expf(ma - M) + sm.ml[partner][1][j] * __expf(mb - M);
    aS[r] = __expf(ma - M);
    invL[r] = 1.f / L;
  }
#pragma unroll
  for (int ct = 0; ct < 16; ++ct)
#pragma unroll
    for (int r = 0; r < 4; ++r) O[ct][r] *= aS[r];

  if (p == 1) {
#pragma unroll
    for (int ct = 0; ct < 16; ++ct)
#pragma unroll
      for (int r = 0; r < 4; ++r)
        sm.u.e.Ocmb[jt_l][quad * 4 + r][ct * 16 + row16] = O[ct][r];
  }
  BAR();
  if (p == 0) {
#pragma unroll
    for (int ct = 0; ct < 16; ++ct)
#pragma unroll
      for (int r = 0; r < 4; ++r) {
        float v = sm.u.e.Ocmb[jt_l][quad * 4 + r][ct * 16 + row16] + O[ct][r];
        sm.u.e.ex[jt_l][quad * 4 + r][ct * 16 + row16] = (f16)(v * invL[r]);
      }
  }
  BAR();   // att tile ready; Ocmb dead -> reusable as h (ex2)

  // ---- MLP + LN, 8 ct per wave (ct-halves split across the parity pair) ----
  half8 af[8];
#pragma unroll
  for (int kc = 0; kc < 8; ++kc)
    af[kc] = *reinterpret_cast<const half8*>(&sm.u.e.ex[jt_l][row16][kc * 32 + quad * 8]);

  f16* ex2 = reinterpret_cast<f16*>(&sm.u.e.Ocmb[0][0][0]);   // [4][16][264] f16, 33 KB

  // GEMM1: h = silu(att @ w1 + b1) -> ex2 (this wave's 8 ct)
#pragma unroll
  for (int q8 = 0; q8 < 8; ++q8) {
    int ct = p * 8 + q8;
    f32x4 acc = {0.f, 0.f, 0.f, 0.f};
    const f16* brow = w1p + ((size_t)ct * 8) * 512 + lane * 8;
#pragma unroll
    for (int kc = 0; kc < 8; ++kc)
      acc = __builtin_amdgcn_mfma_f32_16x16x32_f16(af[kc], ldg8(brow + kc * 512), acc, 0, 0, 0);
    int co = ct * 16 + row16;
    float bb = b1[co];
#pragma unroll
    for (int r = 0; r < 4; ++r) {
      float xg = acc[r] + bb;
      float hh = xg / (1.f + __expf(-xg));  // SiLU
      ex2[((size_t)jt_l * 16 + quad * 4 + r) * 264 + co] = (f16)hh;
    }
  }
  BAR();   // full h tile ready

  half8 hf[8];
#pragma unroll
  for (int kc = 0; kc < 8; ++kc)
    hf[kc] = *reinterpret_cast<const half8*>(&ex2[((size_t)jt_l * 16 + row16) * 264 + kc * 32 + quad * 8]);

  f32x4 acc2[8];
#pragma unroll
  for (int q8 = 0; q8 < 8; ++q8) {
    int ct = p * 8 + q8;
    f32x4 acc = {0.f, 0.f, 0.f, 0.f};
    const f16* brow = w2p + ((size_t)ct * 8) * 512 + lane * 8;
#pragma unroll
    for (int kc = 0; kc < 8; ++kc)
      acc = __builtin_amdgcn_mfma_f32_16x16x32_f16(hf[kc], ldg8(brow + kc * 512), acc, 0, 0, 0);
    float bb = b2[ct * 16 + row16];
#pragma unroll
    for (int r = 0; r < 4; ++r) acc[r] += bb;
    acc2[q8] = acc;
  }

  // LayerNorm over C: per-wave partials (128 channels) + pairwise LDS exchange
  float sum[4] = {0.f, 0.f, 0.f, 0.f}, ssq[4] = {0.f, 0.f, 0.f, 0.f};
#pragma unroll
  for (int q8 = 0; q8 < 8; ++q8)
#pragma unroll
    for (int r = 0; r < 4; ++r) { float xv = acc2[q8][r]; sum[r] += xv; ssq[r] += xv * xv; }
#pragma unroll
  for (int r = 0; r < 4; ++r) {
#pragma unroll
    for (int off = 1; off < 16; off <<= 1) {
      sum[r] += __shfl_xor(sum[r], off, 64);
      ssq[r] += __shfl_xor(ssq[r], off, 64);
    }
  }
  if (row16 == 0) {
#pragma unroll
    for (int r = 0; r < 4; ++r) {
      sm.lnbuf[wave][0][quad * 4 + r] = sum[r];
      sm.lnbuf[wave][1][quad * 4 + r] = ssq[r];
    }
  }
  BAR();

  float mean[4], rstd[4];
#pragma unroll
  for (int r = 0; r < 4; ++r) {
    int j = quad * 4 + r;
    float s  = sm.lnbuf[wave][0][j] + sm.lnbuf[partner][0][j];
    float sq = sm.lnbuf[wave][1][j] + sm.lnbuf[partner][1][j];
    mean[r] = s * (1.f / 256.f);
    float var = sq * (1.f / 256.f) - mean[r] * mean[r];
    rstd[r] = rsqrtf(var + 1e-5f);
  }

  // coalesced stores: this wave's 128 channels
#pragma unroll
  for (int q8 = 0; q8 < 8; ++q8) {
    int col = (p * 8 + q8) * 16 + row16;
    float g = gamma[col], be = beta[col];
    f32x4 v;
#pragma unroll
    for (int r = 0; r < 4; ++r) v[r] = (acc2[q8][r] - mean[r]) * rstd[r] * g + be;
    *reinterpret_cast<f32x4*>(out + (size_t)(bg * CC + col) * NN + jw + quad * 4) = v;
  }
}

extern "C" void kernel_launch(void* const* d_in, const int* in_sizes, int n_in,
                              void* d_out, int out_size, void* d_ws, size_t ws_size,
                              hipStream_t stream) {
  (void)in_sizes; (void)n_in; (void)out_size;
  const float* x     = (const float*)d_in[0];
  const float* wq    = (const float*)d_in[1];
  const float* bq    = (const float*)d_in[2];
  const float* wk    = (const float*)d_in[3];
  const float* bk    = (const float*)d_in[4];
  const float* wv    = (const float*)d_in[5];
  const float* bv    = (const float*)d_in[6];
  const float* w1    = (const float*)d_in[7];
  const float* b1    = (const float*)d_in[8];
  const float* w2    = (const float*)d_in[9];
  const float* b2    = (const float*)d_in[10];
  const float* gamma = (const float*)d_in[11];
  const float* beta  = (const float*)d_in[12];
  float* out = (float*)d_out;

  const size_t WE = 65536;
  const size_t SB = (size_t)NN * CC;
  f16* base = (f16*)d_ws;
  f16* wqp = base + 0 * WE;
  f16* wkp = base + 1 * WE;
  f16* wvp = base + 2 * WE;
  f16* w1p = base + 3 * WE;
  f16* w2p = base + 4 * WE;

  size_t wbytes = 5 * WE * sizeof(f16);
  size_t perb   = 3 * SB * sizeof(f16);
  int nb = (ws_size > wbytes) ? (int)((ws_size - wbytes) / perb) : 1;
  if (nb < 1) nb = 1;
  if (nb > BB) nb = BB;

  f16* qb  = base + 5 * WE;
  f16* kb  = qb + (size_t)nb * SB;
  f16* vTb = kb + (size_t)nb * SB;

  WP5 p;
  p.s[0] = wq; p.s[1] = wk; p.s[2] = wv; p.s[3] = w1; p.s[4] = w2;
  p.d[0] = wqp; p.d[1] = wkp; p.d[2] = wvp; p.d[3] = w1p; p.d[4] = w2p;
  k_packW<<<dim3(16, 5), 256, 0, stream>>>(p);

  for (int b0 = 0; b0 < BB; b0 += nb) {
    int cb = (b0 + nb <= BB) ? nb : (BB - b0);
    k_qkv<<<dim3(cb, 32), 256, 0, stream>>>(x, wqp, wkp, wvp, bq, bk, bv, qb, kb, vTb, b0);
    k_attn_mlp<<<dim3(cb, 16), 512, 0, stream>>>(qb, kb, vTb, w1p, b1, w2p, b2,
                                                 gamma, beta, out, b0);
  }
}

// Round 10
// 187.040 us; speedup vs baseline: 1.0378x; 1.0378x over previous
//
#include <hip/hip_runtime.h>

#define BB 16
#define CC 256
#define NN 1024

typedef _Float16 f16;
typedef __attribute__((ext_vector_type(8))) _Float16 half8;   // MFMA A/B frag (4 VGPRs)
typedef __attribute__((ext_vector_type(4))) float f32x4;      // MFMA C/D frag

__device__ __forceinline__ half8 ldg8(const f16* p) {
  return *reinterpret_cast<const half8*>(p);
}

// async global->LDS, 16B per lane; lds base must be wave-uniform (HW adds lane*16)
__device__ __forceinline__ void gll16(const f16* g, f16* l) {
  __builtin_amdgcn_global_load_lds((const __attribute__((address_space(1))) void*)g,
                                   (__attribute__((address_space(3))) void*)l, 16, 0, 0);
}

#define VMCNT(n) asm volatile("s_waitcnt vmcnt(" #n ")" ::: "memory")
#define BAR() __builtin_amdgcn_s_barrier()

// stage one contiguous 32 KB chunk (16384 f16) with 512 threads (8 waves): 4 issues/thread.
__device__ __forceinline__ void stage32k8(const f16* __restrict__ g, f16* l, int wave, int lane) {
#pragma unroll
  for (int k = 0; k < 4; ++k) {
    int ob = k * 4096 + wave * 512;      // 8 waves x 512 = 4096 per k
    gll16(g + ob + lane * 8, l + ob);
  }
}

// ---------------- weight pack: W fp32 [ci][co] -> frag-packed f16 wp[(ct*8+kc)*512 + lane*8] ----
struct WP5 {
  const float* s[5];
  f16* d[5];
};

__global__ void __launch_bounds__(256) k_packW(WP5 p) {
  __shared__ float ws[256][17];
  int m = blockIdx.y, ct = blockIdx.x;
  const float* W = p.s[m];
  f16* wp = p.d[m];
  int tid = threadIdx.x;
  int col = tid & 15, cig = tid >> 4;
#pragma unroll
  for (int pg = 0; pg < 16; ++pg) {
    int ci = pg * 16 + cig;
    ws[ci][col] = W[(size_t)ci * 256 + ct * 16 + col];
  }
  __syncthreads();
  int lane = tid & 63, wave = tid >> 6;
  int row16 = lane & 15, quad = lane >> 4;
#pragma unroll
  for (int kk = 0; kk < 2; ++kk) {
    int kc = wave * 2 + kk;
    half8 o;
#pragma unroll
    for (int j = 0; j < 8; ++j) o[j] = (f16)ws[kc * 32 + quad * 8 + j][row16];
    *reinterpret_cast<half8*>(wp + ((size_t)ct * 8 + kc) * 512 + lane * 8) = o;
  }
}

// ---------------- QKV, R10: 2-WAY z-SPLIT for TLP ----------------
// R9 post-mortem: qkv at grid (16,32)=512 blocks is 2 blocks/CU BY CONSTRUCTION — the same
// 2-waves/SIMD latency exposure attn had. R2<->R3 showed z-merge (3x less TLP, 3x less
// redundant x-convert) was NEUTRAL: TLP gain ~ redundancy cost. So split 2-way:
// z=0 computes {q,k}, z=1 computes {v} -> 1024 blocks = 4 blocks/CU (LDS 33.8 KB x 4 fits),
// only 2x x-convert redundancy. (256,4): both plausible 2nd-arg semantics (min-blocks/CU,
// waves/EU) yield a 128-VGPR budget; acc loop restructured 4 -> 2x2 to fit (~116 live).
// Also reverts R9's (256,2) anomaly (+11 us on total).
struct QkvSmem {
  union {
    struct { f16 hi[32][264]; f16 lo[32][264]; } ts;
    f16 ex[2][16][264];
    f16 exv[256][40];
  };
};

__global__ void __launch_bounds__(256, 4) k_qkv(const float* __restrict__ x,
    const f16* __restrict__ wqp, const f16* __restrict__ wkp, const f16* __restrict__ wvp,
    const float* __restrict__ bq, const float* __restrict__ bk, const float* __restrict__ bv,
    f16* __restrict__ qp, f16* __restrict__ kp, f16* __restrict__ vp, int b_base) {
  __shared__ QkvSmem sm;
  int z = blockIdx.z;
  int bl = blockIdx.x, bg = b_base + bl, n0 = blockIdx.y * 32;
  int tid = threadIdx.x, wave = tid >> 6, lane = tid & 63;
  int row16 = lane & 15, quad = lane >> 4;
  int g = wave >> 1, h = wave & 1;

  // ---- load x chunk once; split into hi/lo f16 halves, transposed into LDS ----
#pragma unroll
  for (int e = tid; e < 2048; e += 256) {
    int c = e >> 3, n4 = (e & 7) << 2;
    float4 u = *reinterpret_cast<const float4*>(x + (size_t)(bg * CC + c) * NN + n0 + n4);
    float uv[4] = {u.x, u.y, u.z, u.w};
#pragma unroll
    for (int i = 0; i < 4; ++i) {
      f16 hh = (f16)uv[i];
      sm.ts.hi[n4 + i][c] = hh;
      sm.ts.lo[n4 + i][c] = (f16)(uv[i] - (float)hh);
    }
  }
  __syncthreads();

  half8 ah[8], al[8];
#pragma unroll
  for (int kc = 0; kc < 8; ++kc) {
    ah[kc] = *reinterpret_cast<const half8*>(&sm.ts.hi[g * 16 + row16][kc * 32 + quad * 8]);
    al[kc] = *reinterpret_cast<const half8*>(&sm.ts.lo[g * 16 + row16][kc * 32 + quad * 8]);
  }
  __syncthreads();

  if (z == 0) {
    // ---- q then k: ex reuse is wave-local (each h-wave reads the co-half it wrote) ----
    const f16* WTs[2]      = {wqp, wkp};
    const float* biases[2] = {bq, bk};
    f16* outs[2]           = {qp, kp};
#pragma unroll
    for (int zz = 0; zz < 2; ++zz) {
      const f16* WT = WTs[zz];
      const float* bias = biases[zz];
      f16* outp = outs[zz];
#pragma unroll
      for (int cp = 0; cp < 2; ++cp) {
#pragma unroll
        for (int uu = 0; uu < 2; ++uu) {
          f32x4 acch[2], accl[2];
#pragma unroll
          for (int u = 0; u < 2; ++u) { acch[u] = {0.f,0.f,0.f,0.f}; accl[u] = {0.f,0.f,0.f,0.f}; }
#pragma unroll
          for (int kc = 0; kc < 8; ++kc) {
#pragma unroll
            for (int u = 0; u < 2; ++u) {
              int ct = h * 8 + cp * 4 + uu * 2 + u;
              half8 b = ldg8(WT + ((size_t)ct * 8 + kc) * 512 + lane * 8);
              acch[u] = __builtin_amdgcn_mfma_f32_16x16x32_f16(ah[kc], b, acch[u], 0, 0, 0);
              accl[u] = __builtin_amdgcn_mfma_f32_16x16x32_f16(al[kc], b, accl[u], 0, 0, 0);
            }
          }
#pragma unroll
          for (int u = 0; u < 2; ++u) {
            int ct = h * 8 + cp * 4 + uu * 2 + u;
            int co = ct * 16 + row16;
            float bb = bias[co];
#pragma unroll
            for (int r = 0; r < 4; ++r)
              sm.ex[g][quad * 4 + r][co] = (f16)(acch[u][r] + accl[u][r] + bb);
          }
        }
      }
      const f16* exr = &sm.ex[g][row16][0];
      size_t fb = ((size_t)bl * 64 + (n0 >> 4) + g) * 8;
#pragma unroll
      for (int k = 0; k < 4; ++k) {
        int kc = h * 4 + k;
        half8 hv = *reinterpret_cast<const half8*>(exr + kc * 32 + quad * 8);
        *reinterpret_cast<half8*>(outp + (fb + kc) * 512 + lane * 8) = hv;
      }
    }
  } else {
    // ---- v: transposed epilogue into exv, then packed vT store ----
#pragma unroll
    for (int cp = 0; cp < 2; ++cp) {
#pragma unroll
      for (int uu = 0; uu < 2; ++uu) {
        f32x4 acch[2], accl[2];
#pragma unroll
        for (int u = 0; u < 2; ++u) { acch[u] = {0.f,0.f,0.f,0.f}; accl[u] = {0.f,0.f,0.f,0.f}; }
#pragma unroll
        for (int kc = 0; kc < 8; ++kc) {
#pragma unroll
          for (int u = 0; u < 2; ++u) {
            int ct = h * 8 + cp * 4 + uu * 2 + u;
            half8 b = ldg8(wvp + ((size_t)ct * 8 + kc) * 512 + lane * 8);
            acch[u] = __builtin_amdgcn_mfma_f32_16x16x32_f16(ah[kc], b, acch[u], 0, 0, 0);
            accl[u] = __builtin_amdgcn_mfma_f32_16x16x32_f16(al[kc], b, accl[u], 0, 0, 0);
          }
        }
#pragma unroll
        for (int u = 0; u < 2; ++u) {
          int ct = h * 8 + cp * 4 + uu * 2 + u;
          int co = ct * 16 + row16;
          float bb = bv[co];
#pragma unroll
          for (int r = 0; r < 4; ++r)
            sm.exv[co][g * 16 + quad * 4 + r] = (f16)(acch[u][r] + accl[u][r] + bb);
        }
      }
    }
    __syncthreads();
    size_t vb = ((size_t)bl * 32 + blockIdx.y) * 16;
#pragma unroll
    for (int f = 0; f < 4; ++f) {
      int ct = wave * 4 + f;
      half8 o = *reinterpret_cast<const half8*>(&sm.exv[ct * 16 + row16][quad * 8]);
      *reinterpret_cast<half8*>(vp + (vb + ct) * 512 + lane * 8) = o;
    }
  }
}

// ---------------- fused flash attention + MLP(SiLU) + LayerNorm ----------------
// R10 = R9 + EXACT skip-rescale: when no j-row in the wave has a new max (mx <= m_run
// for all r), alpha would be exp(0)=1 exactly -> skip the 64 O-mults + 4 exp via one
// wave-uniform __any branch. Bit-exact; after the max stabilizes (~4 its) most of the
// 16 iterations skip. Targets the measured VALU tail (VALUBusy 26%).
struct AttnSmem {
  union {
    struct {
      f16 QB[2][64 * 256];     // 2 x 32 KB: packed q frags, double-buffered 64-i chunks
      f16 VB[2][64 * 256];     // 2 x 32 KB: packed vT frags
    } s;
    struct {
      float Ocmb[4][16][260];  // 66.6 KB: pairwise O-combine (f32); later aliased as h
      f16 ex[4][16][264];      // 33 KB: normalized att
    } e;
  } u;                      // 131072 B
  f16 P[8][16][40];         // per-wave P round-trip (C->A layout)  10240 B
  float ml[8][2][16];       // per-wave {m, l} per j-row             1024 B
  float lnbuf[8][2][16];    // per-wave LN partials {sum, ssq}       1024 B
};                          // total 143360 B (1 block/CU)

__global__ void __launch_bounds__(512, 2) k_attn_mlp(
    const f16* __restrict__ qp, const f16* __restrict__ kp, const f16* __restrict__ vp,
    const f16* __restrict__ w1p, const float* __restrict__ b1,
    const f16* __restrict__ w2p, const float* __restrict__ b2,
    const float* __restrict__ gamma, const float* __restrict__ beta,
    float* __restrict__ out, int b_base) {
  __shared__ AttnSmem sm;
  int bl = blockIdx.x, bg = b_base + bl;
  int j0 = blockIdx.y * 64;
  int tid = threadIdx.x, wave = tid >> 6, lane = tid & 63;
  int row16 = lane & 15, quad = lane >> 4;
  int jt_l = wave & 3, p = wave >> 2;        // j-tile within block, i-parity (0..1)
  int jw = j0 + jt_l * 16;

  // A-frags: k rows of this wave's j-tile (parity partner loads the same rows; L2-hot)
  const f16* kbase = kp + (size_t)bl * NN * CC;
  int jt = (j0 >> 4) + jt_l;
  half8 kf[8];
#pragma unroll
  for (int kc = 0; kc < 8; ++kc)
    kf[kc] = ldg8(kbase + ((size_t)jt * 8 + kc) * 512 + lane * 8);

  const f16* qbase = qp + (size_t)bl * NN * CC;
  const f16* vbase = vp + (size_t)bl * CC * NN;

  // prologue: stage chunk 0 into buffer 0; drain everything (kf included)
  stage32k8(qbase, sm.u.s.QB[0], wave, lane);
  stage32k8(vbase, sm.u.s.VB[0], wave, lane);
  VMCNT(0);
  BAR();

  f32x4 O[16];
#pragma unroll
  for (int ct = 0; ct < 16; ++ct) O[ct] = {0.f, 0.f, 0.f, 0.f};
  float m_run[4], l_lane[4];
#pragma unroll
  for (int r = 0; r < 4; ++r) { m_run[r] = -1e30f; l_lane[r] = 0.f; }

  int cur = 0;
  for (int it = 0; it < 16; ++it) {
    const f16* QBp = &sm.u.s.QB[cur][p * 8192];   // parity's 32 rows = 16 frags
    const f16* VBp = &sm.u.s.VB[cur][p * 8192];

    // issue next-chunk staging into the other buffer — a full iteration to land.
    stage32k8(qbase + (size_t)((it + 1) & 15) * 16384, sm.u.s.QB[cur ^ 1], wave, lane);
    stage32k8(vbase + (size_t)((it + 1) & 15) * 16384, sm.u.s.VB[cur ^ 1], wave, lane);

    // ---- QK: scores S[16 j][32 i] from LDS, 2 parallel MFMA chains ----
    f32x4 s[2];
#pragma unroll
    for (int f = 0; f < 2; ++f) s[f] = {0.f, 0.f, 0.f, 0.f};
#pragma unroll
    for (int kc = 0; kc < 8; ++kc) {
#pragma unroll
      for (int f = 0; f < 2; ++f) {
        half8 b = *reinterpret_cast<const half8*>(&QBp[(f * 8 + kc) * 512 + lane * 8]);
        s[f] = __builtin_amdgcn_mfma_f32_16x16x32_f16(kf[kc], b, s[f], 0, 0, 0);
      }
    }

    // ---- softmax per j-row over this wave's 32 i, with exact skip-rescale ----
    float mx4[4];
    bool need = false;
#pragma unroll
    for (int r = 0; r < 4; ++r) {
      float mx = fmaxf(s[0][r], s[1][r]);
#pragma unroll
      for (int off = 1; off < 16; off <<= 1) mx = fmaxf(mx, __shfl_xor(mx, off, 64));
      mx4[r] = mx;
      need = need || (mx > m_run[r]);
    }
    if (__any(need)) {   // some row has a new max: rescale (alpha != 1 somewhere)
      float alpha[4];
#pragma unroll
      for (int r = 0; r < 4; ++r) {
        float mnew = fmaxf(m_run[r], mx4[r]);
        alpha[r] = __expf(m_run[r] - mnew);
        m_run[r] = mnew;
        l_lane[r] *= alpha[r];
      }
#pragma unroll
      for (int ct = 0; ct < 16; ++ct)
#pragma unroll
        for (int r = 0; r < 4; ++r) O[ct][r] *= alpha[r];
    }
    // P-write + l accumulation (always; exact: s <= m_run when skipped)
#pragma unroll
    for (int r = 0; r < 4; ++r) {
      float ps = 0.f;
#pragma unroll
      for (int f = 0; f < 2; ++f) {
        float pv = __expf(s[f][r] - m_run[r]);
        ps += pv;
        sm.P[wave][quad * 4 + r][f * 16 + row16] = (f16)pv;
      }
      l_lane[r] += ps;
    }

    // ---- PV: one 32-i chunk; P same-wave LDS round-trip, vT frags from LDS ----
    {
      half8 pf = *reinterpret_cast<const half8*>(&sm.P[wave][row16][quad * 8]);
#pragma unroll
      for (int ct = 0; ct < 16; ++ct) {
        half8 vf = *reinterpret_cast<const half8*>(&VBp[ct * 512 + lane * 8]);
        O[ct] = __builtin_amdgcn_mfma_f32_16x16x32_f16(pf, vf, O[ct], 0, 0, 0);
      }
    }

    VMCNT(0);   // next chunk landed (it had the whole iteration to fly)
    BAR();      // all waves done reading buf[cur]; staged data visible
    cur ^= 1;
  }

  // ---- pairwise (m, l, O) combine across parity waves ----
#pragma unroll
  for (int r = 0; r < 4; ++r) {
#pragma unroll
    for (int off = 1; off < 16; off <<= 1) l_lane[r] += __shfl_xor(l_lane[r], off, 64);
  }
  if (row16 == 0) {
#pragma unroll
    for (int r = 0; r < 4; ++r) {
      sm.ml[wave][0][quad * 4 + r] = m_run[r];
      sm.ml[wave][1][quad * 4 + r] = l_lane[r];
    }
  }
  BAR();

  int partner = wave ^ 4;
  float aS[4], invL[4];
#pragma unroll
  for (int r = 0; r < 4; ++r) {
    int j = quad * 4 + r;
    float ma = m_run[r], mb = sm.ml[partner][0][j];
    float M = fmaxf(ma, mb);
    float L = l_lane[r] * __expf(ma - M) + sm.ml[partner][1][j] * __expf(mb - M);
    aS[r] = __expf(ma - M);
    invL[r] = 1.f / L;
  }
#pragma unroll
  for (int ct = 0; ct < 16; ++ct)
#pragma unroll
    for (int r = 0; r < 4; ++r) O[ct][r] *= aS[r];

  if (p == 1) {
#pragma unroll
    for (int ct = 0; ct < 16; ++ct)
#pragma unroll
      for (int r = 0; r < 4; ++r)
        sm.u.e.Ocmb[jt_l][quad * 4 + r][ct * 16 + row16] = O[ct][r];
  }
  BAR();
  if (p == 0) {
#pragma unroll
    for (int ct = 0; ct < 16; ++ct)
#pragma unroll
      for (int r = 0; r < 4; ++r) {
        float v = sm.u.e.Ocmb[jt_l][quad * 4 + r][ct * 16 + row16] + O[ct][r];
        sm.u.e.ex[jt_l][quad * 4 + r][ct * 16 + row16] = (f16)(v * invL[r]);
      }
  }
  BAR();   // att tile ready; Ocmb dead -> reusable as h (ex2)

  // ---- MLP + LN, 8 ct per wave (ct-halves split across the parity pair) ----
  half8 af[8];
#pragma unroll
  for (int kc = 0; kc < 8; ++kc)
    af[kc] = *reinterpret_cast<const half8*>(&sm.u.e.ex[jt_l][row16][kc * 32 + quad * 8]);

  f16* ex2 = reinterpret_cast<f16*>(&sm.u.e.Ocmb[0][0][0]);   // [4][16][264] f16, 33 KB

  // GEMM1: h = silu(att @ w1 + b1) -> ex2 (this wave's 8 ct)
#pragma unroll
  for (int q8 = 0; q8 < 8; ++q8) {
    int ct = p * 8 + q8;
    f32x4 acc = {0.f, 0.f, 0.f, 0.f};
    const f16* brow = w1p + ((size_t)ct * 8) * 512 + lane * 8;
#pragma unroll
    for (int kc = 0; kc < 8; ++kc)
      acc = __builtin_amdgcn_mfma_f32_16x16x32_f16(af[kc], ldg8(brow + kc * 512), acc, 0, 0, 0);
    int co = ct * 16 + row16;
    float bb = b1[co];
#pragma unroll
    for (int r = 0; r < 4; ++r) {
      float xg = acc[r] + bb;
      float hh = xg / (1.f + __expf(-xg));  // SiLU
      ex2[((size_t)jt_l * 16 + quad * 4 + r) * 264 + co] = (f16)hh;
    }
  }
  BAR();   // full h tile ready

  half8 hf[8];
#pragma unroll
  for (int kc = 0; kc < 8; ++kc)
    hf[kc] = *reinterpret_cast<const half8*>(&ex2[((size_t)jt_l * 16 + row16) * 264 + kc * 32 + quad * 8]);

  f32x4 acc2[8];
#pragma unroll
  for (int q8 = 0; q8 < 8; ++q8) {
    int ct = p * 8 + q8;
    f32x4 acc = {0.f, 0.f, 0.f, 0.f};
    const f16* brow = w2p + ((size_t)ct * 8) * 512 + lane * 8;
#pragma unroll
    for (int kc = 0; kc < 8; ++kc)
      acc = __builtin_amdgcn_mfma_f32_16x16x32_f16(hf[kc], ldg8(brow + kc * 512), acc, 0, 0, 0);
    float bb = b2[ct * 16 + row16];
#pragma unroll
    for (int r = 0; r < 4; ++r) acc[r] += bb;
    acc2[q8] = acc;
  }

  // LayerNorm over C: per-wave partials (128 channels) + pairwise LDS exchange
  float sum[4] = {0.f, 0.f, 0.f, 0.f}, ssq[4] = {0.f, 0.f, 0.f, 0.f};
#pragma unroll
  for (int q8 = 0; q8 < 8; ++q8)
#pragma unroll
    for (int r = 0; r < 4; ++r) { float xv = acc2[q8][r]; sum[r] += xv; ssq[r] += xv * xv; }
#pragma unroll
  for (int r = 0; r < 4; ++r) {
#pragma unroll
    for (int off = 1; off < 16; off <<= 1) {
      sum[r] += __shfl_xor(sum[r], off, 64);
      ssq[r] += __shfl_xor(ssq[r], off, 64);
    }
  }
  if (row16 == 0) {
#pragma unroll
    for (int r = 0; r < 4; ++r) {
      sm.lnbuf[wave][0][quad * 4 + r] = sum[r];
      sm.lnbuf[wave][1][quad * 4 + r] = ssq[r];
    }
  }
  BAR();

  float mean[4], rstd[4];
#pragma unroll
  for (int r = 0; r < 4; ++r) {
    int j = quad * 4 + r;
    float s  = sm.lnbuf[wave][0][j] + sm.lnbuf[partner][0][j];
    float sq = sm.lnbuf[wave][1][j] + sm.lnbuf[partner][1][j];
    mean[r] = s * (1.f / 256.f);
    float var = sq * (1.f / 256.f) - mean[r] * mean[r];
    rstd[r] = rsqrtf(var + 1e-5f);
  }

  // coalesced stores: this wave's 128 channels
#pragma unroll
  for (int q8 = 0; q8 < 8; ++q8) {
    int col = (p * 8 + q8) * 16 + row16;
    float g = gamma[col], be = beta[col];
    f32x4 v;
#pragma unroll
    for (int r = 0; r < 4; ++r) v[r] = (acc2[q8][r] - mean[r]) * rstd[r] * g + be;
    *reinterpret_cast<f32x4*>(out + (size_t)(bg * CC + col) * NN + jw + quad * 4) = v;
  }
}

extern "C" void kernel_launch(void* const* d_in, const int* in_sizes, int n_in,
                              void* d_out, int out_size, void* d_ws, size_t ws_size,
                              hipStream_t stream) {
  (void)in_sizes; (void)n_in; (void)out_size;
  const float* x     = (const float*)d_in[0];
  const float* wq    = (const float*)d_in[1];
  const float* bq    = (const float*)d_in[2];
  const float* wk    = (const float*)d_in[3];
  const float* bk    = (const float*)d_in[4];
  const float* wv    = (const float*)d_in[5];
  const float* bv    = (const float*)d_in[6];
  const float* w1    = (const float*)d_in[7];
  const float* b1    = (const float*)d_in[8];
  const float* w2    = (const float*)d_in[9];
  const float* b2    = (const float*)d_in[10];
  const float* gamma = (const float*)d_in[11];
  const float* beta  = (const float*)d_in[12];
  float* out = (float*)d_out;

  const size_t WE = 65536;
  const size_t SB = (size_t)NN * CC;
  f16* base = (f16*)d_ws;
  f16* wqp = base + 0 * WE;
  f16* wkp = base + 1 * WE;
  f16* wvp = base + 2 * WE;
  f16* w1p = base + 3 * WE;
  f16* w2p = base + 4 * WE;

  size_t wbytes = 5 * WE * sizeof(f16);
  size_t perb   = 3 * SB * sizeof(f16);
  int nb = (ws_size > wbytes) ? (int)((ws_size - wbytes) / perb) : 1;
  if (nb < 1) nb = 1;
  if (nb > BB) nb = BB;

  f16* qb  = base + 5 * WE;
  f16* kb  = qb + (size_t)nb * SB;
  f16* vTb = kb + (size_t)nb * SB;

  WP5 p;
  p.s[0] = wq; p.s[1] = wk; p.s[2] = wv; p.s[3] = w1; p.s[4] = w2;
  p.d[0] = wqp; p.d[1] = wkp; p.d[2] = wvp; p.d[3] = w1p; p.d[4] = w2p;
  k_packW<<<dim3(16, 5), 256, 0, stream>>>(p);

  for (int b0 = 0; b0 < BB; b0 += nb) {
    int cb = (b0 + nb <= BB) ? nb : (BB - b0);
    k_qkv<<<dim3(cb, 32, 2), 256, 0, stream>>>(x, wqp, wkp, wvp, bq, bk, bv, qb, kb, vTb, b0);
    k_attn_mlp<<<dim3(cb, 16), 512, 0, stream>>>(qb, kb, vTb, w1p, b1, w2p, b2,
                                                 gamma, beta, out, b0);
  }
}

// Round 11
// 183.259 us; speedup vs baseline: 1.0592x; 1.0206x over previous
//
#include <hip/hip_runtime.h>

#define BB 16
#define CC 256
#define NN 1024

typedef _Float16 f16;
typedef __attribute__((ext_vector_type(8))) _Float16 half8;   // MFMA A/B frag (4 VGPRs)
typedef __attribute__((ext_vector_type(4))) float f32x4;      // MFMA C/D frag

__device__ __forceinline__ half8 ldg8(const f16* p) {
  return *reinterpret_cast<const half8*>(p);
}

// async global->LDS, 16B per lane; lds base must be wave-uniform (HW adds lane*16)
__device__ __forceinline__ void gll16(const f16* g, f16* l) {
  __builtin_amdgcn_global_load_lds((const __attribute__((address_space(1))) void*)g,
                                   (__attribute__((address_space(3))) void*)l, 16, 0, 0);
}

#define VMCNT(n) asm volatile("s_waitcnt vmcnt(" #n ")" ::: "memory")
#define BAR() __builtin_amdgcn_s_barrier()

// stage one contiguous 64 KB chunk with 512 threads (8 waves): 8 issues/thread.
__device__ __forceinline__ void stage64k8(const f16* __restrict__ g, f16* l, int wave, int lane) {
#pragma unroll
  for (int k = 0; k < 8; ++k) {
    int ob = k * 4096 + wave * 512;      // 8 waves x 512 = 4096 per k
    gll16(g + ob + lane * 8, l + ob);
  }
}

// ---------------- weight pack: W fp32 [ci][co] -> frag-packed f16 wp[(ct*8+kc)*512 + lane*8] ----
struct WP5 {
  const float* s[5];
  f16* d[5];
};

__global__ void __launch_bounds__(256) k_packW(WP5 p) {
  __shared__ float ws[256][17];
  int m = blockIdx.y, ct = blockIdx.x;
  const float* W = p.s[m];
  f16* wp = p.d[m];
  int tid = threadIdx.x;
  int col = tid & 15, cig = tid >> 4;
#pragma unroll
  for (int pg = 0; pg < 16; ++pg) {
    int ci = pg * 16 + cig;
    ws[ci][col] = W[(size_t)ci * 256 + ct * 16 + col];
  }
  __syncthreads();
  int lane = tid & 63, wave = tid >> 6;
  int row16 = lane & 15, quad = lane >> 4;
#pragma unroll
  for (int kk = 0; kk < 2; ++kk) {
    int kc = wave * 2 + kk;
    half8 o;
#pragma unroll
    for (int j = 0; j < 8; ++j) o[j] = (f16)ws[kc * 32 + quad * 8 + j][row16];
    *reinterpret_cast<half8*>(wp + ((size_t)ct * 8 + kc) * 512 + lane * 8) = o;
  }
}

// ---------------- QKV, 2-way z-split (R10, proven -11.5 us) ----------------
struct QkvSmem {
  union {
    struct { f16 hi[32][264]; f16 lo[32][264]; } ts;
    f16 ex[2][16][264];
    f16 exv[256][40];
  };
};

__global__ void __launch_bounds__(256, 4) k_qkv(const float* __restrict__ x,
    const f16* __restrict__ wqp, const f16* __restrict__ wkp, const f16* __restrict__ wvp,
    const float* __restrict__ bq, const float* __restrict__ bk, const float* __restrict__ bv,
    f16* __restrict__ qp, f16* __restrict__ kp, f16* __restrict__ vp, int b_base) {
  __shared__ QkvSmem sm;
  int z = blockIdx.z;
  int bl = blockIdx.x, bg = b_base + bl, n0 = blockIdx.y * 32;
  int tid = threadIdx.x, wave = tid >> 6, lane = tid & 63;
  int row16 = lane & 15, quad = lane >> 4;
  int g = wave >> 1, h = wave & 1;

  // ---- load x chunk once; split into hi/lo f16 halves, transposed into LDS ----
#pragma unroll
  for (int e = tid; e < 2048; e += 256) {
    int c = e >> 3, n4 = (e & 7) << 2;
    float4 u = *reinterpret_cast<const float4*>(x + (size_t)(bg * CC + c) * NN + n0 + n4);
    float uv[4] = {u.x, u.y, u.z, u.w};
#pragma unroll
    for (int i = 0; i < 4; ++i) {
      f16 hh = (f16)uv[i];
      sm.ts.hi[n4 + i][c] = hh;
      sm.ts.lo[n4 + i][c] = (f16)(uv[i] - (float)hh);
    }
  }
  __syncthreads();

  half8 ah[8], al[8];
#pragma unroll
  for (int kc = 0; kc < 8; ++kc) {
    ah[kc] = *reinterpret_cast<const half8*>(&sm.ts.hi[g * 16 + row16][kc * 32 + quad * 8]);
    al[kc] = *reinterpret_cast<const half8*>(&sm.ts.lo[g * 16 + row16][kc * 32 + quad * 8]);
  }
  __syncthreads();

  if (z == 0) {
    // ---- q then k: ex reuse is wave-local ----
    const f16* WTs[2]      = {wqp, wkp};
    const float* biases[2] = {bq, bk};
    f16* outs[2]           = {qp, kp};
#pragma unroll
    for (int zz = 0; zz < 2; ++zz) {
      const f16* WT = WTs[zz];
      const float* bias = biases[zz];
      f16* outp = outs[zz];
#pragma unroll
      for (int cp = 0; cp < 2; ++cp) {
#pragma unroll
        for (int uu = 0; uu < 2; ++uu) {
          f32x4 acch[2], accl[2];
#pragma unroll
          for (int u = 0; u < 2; ++u) { acch[u] = {0.f,0.f,0.f,0.f}; accl[u] = {0.f,0.f,0.f,0.f}; }
#pragma unroll
          for (int kc = 0; kc < 8; ++kc) {
#pragma unroll
            for (int u = 0; u < 2; ++u) {
              int ct = h * 8 + cp * 4 + uu * 2 + u;
              half8 b = ldg8(WT + ((size_t)ct * 8 + kc) * 512 + lane * 8);
              acch[u] = __builtin_amdgcn_mfma_f32_16x16x32_f16(ah[kc], b, acch[u], 0, 0, 0);
              accl[u] = __builtin_amdgcn_mfma_f32_16x16x32_f16(al[kc], b, accl[u], 0, 0, 0);
            }
          }
#pragma unroll
          for (int u = 0; u < 2; ++u) {
            int ct = h * 8 + cp * 4 + uu * 2 + u;
            int co = ct * 16 + row16;
            float bb = bias[co];
#pragma unroll
            for (int r = 0; r < 4; ++r)
              sm.ex[g][quad * 4 + r][co] = (f16)(acch[u][r] + accl[u][r] + bb);
          }
        }
      }
      const f16* exr = &sm.ex[g][row16][0];
      size_t fb = ((size_t)bl * 64 + (n0 >> 4) + g) * 8;
#pragma unroll
      for (int k = 0; k < 4; ++k) {
        int kc = h * 4 + k;
        half8 hv = *reinterpret_cast<const half8*>(exr + kc * 32 + quad * 8);
        *reinterpret_cast<half8*>(outp + (fb + kc) * 512 + lane * 8) = hv;
      }
    }
  } else {
    // ---- v: transposed epilogue into exv, then packed vT store ----
#pragma unroll
    for (int cp = 0; cp < 2; ++cp) {
#pragma unroll
      for (int uu = 0; uu < 2; ++uu) {
        f32x4 acch[2], accl[2];
#pragma unroll
        for (int u = 0; u < 2; ++u) { acch[u] = {0.f,0.f,0.f,0.f}; accl[u] = {0.f,0.f,0.f,0.f}; }
#pragma unroll
        for (int kc = 0; kc < 8; ++kc) {
#pragma unroll
          for (int u = 0; u < 2; ++u) {
            int ct = h * 8 + cp * 4 + uu * 2 + u;
            half8 b = ldg8(wvp + ((size_t)ct * 8 + kc) * 512 + lane * 8);
            acch[u] = __builtin_amdgcn_mfma_f32_16x16x32_f16(ah[kc], b, acch[u], 0, 0, 0);
            accl[u] = __builtin_amdgcn_mfma_f32_16x16x32_f16(al[kc], b, accl[u], 0, 0, 0);
          }
        }
#pragma unroll
        for (int u = 0; u < 2; ++u) {
          int ct = h * 8 + cp * 4 + uu * 2 + u;
          int co = ct * 16 + row16;
          float bb = bv[co];
#pragma unroll
          for (int r = 0; r < 4; ++r)
            sm.exv[co][g * 16 + quad * 4 + r] = (f16)(acch[u][r] + accl[u][r] + bb);
        }
      }
    }
    __syncthreads();
    size_t vb = ((size_t)bl * 32 + blockIdx.y) * 16;
#pragma unroll
    for (int f = 0; f < 4; ++f) {
      int ct = wave * 4 + f;
      half8 o = *reinterpret_cast<const half8*>(&sm.exv[ct * 16 + row16][quad * 8]);
      *reinterpret_cast<half8*>(vp + (vb + ct) * 512 + lane * 8) = o;
    }
  }
}

// ---------------- fused flash attention + MLP(SiLU) + LayerNorm ----------------
// R11 = R4 kernel verbatim (proven 53.5-55.4 us) with plain stores (not nontemporal).
// Structure: 8 waves = 4 j-tiles x 2 i-parities; per iteration the block stages one
// 128-i Q chunk + V chunk; each parity consumes 64 i with s[4] (8 softmax steps total —
// the R4<->R8/R9/R10 ladder proved per-softmax-step fixed cost dominates sync count:
// 8 fat steps (54 us) beat 16 thin steps (59.7-64.7 us) at every sync cadence).
// Counted vmcnt(8) keeps the next chunk's 8 loads in flight across barriers.
struct AttnSmem {
  union {
    struct {
      f16 QB[2][64 * 256];   // 2 x 32 KB: packed q frags, chunk parity 0/1
      f16 VB[2][64 * 256];   // 2 x 32 KB: packed vT frags
    } s;
    struct {
      union {
        float Ocmb[4][16][260];   // 66.6 KB: pairwise O-combine (f32)
        f16 ex2[4][16][264];      // 33 KB: MLP hidden h (aliases Ocmb, used after)
      } a;
      f16 ex[4][16][264];         // 33 KB: normalized att per j-tile
    } e;
  } u;                        // 128 KB
  f16 P[8][2][16][40];        // per-wave P round-trip (C->A layout)   20.5 KB
  float ml[8][2][16];         // per-wave {m, l} per j-row              1 KB
  float lnbuf[8][2][16];      // per-wave LN partials {sum, ssq}        1 KB
};

__global__ void __launch_bounds__(512, 2) k_attn_mlp(
    const f16* __restrict__ qp, const f16* __restrict__ kp, const f16* __restrict__ vp,
    const f16* __restrict__ w1p, const float* __restrict__ b1,
    const f16* __restrict__ w2p, const float* __restrict__ b2,
    const float* __restrict__ gamma, const float* __restrict__ beta,
    float* __restrict__ out, int b_base) {
  __shared__ AttnSmem sm;
  int bl = blockIdx.x, bg = b_base + bl;
  int j0 = blockIdx.y * 64;
  int tid = threadIdx.x, wave = tid >> 6, lane = tid & 63;
  int row16 = lane & 15, quad = lane >> 4;
  int jt_l = wave & 3, p = wave >> 2;        // j-tile within block, i-chunk parity
  int jw = j0 + jt_l * 16;

  // A-frags: k rows of this wave's j-tile (partner waves load the same rows; L2-hot)
  const f16* kbase = kp + (size_t)bl * NN * CC;
  int jt = (j0 >> 4) + jt_l;
  half8 kf[8];
#pragma unroll
  for (int kc = 0; kc < 8; ++kc)
    kf[kc] = ldg8(kbase + ((size_t)jt * 8 + kc) * 512 + lane * 8);

  const f16* qbase = qp + (size_t)bl * NN * CC;
  const f16* vbase = vp + (size_t)bl * CC * NN;

  // prologue: stage chunk pair 0 (chunks 0,1 = 64 KB) of Q and V
  stage64k8(qbase, &sm.u.s.QB[0][0], wave, lane);
  stage64k8(vbase, &sm.u.s.VB[0][0], wave, lane);
  VMCNT(8);   // kf(8) + Q(8) drained, V(8) in flight
  BAR();

  f32x4 O[16];
#pragma unroll
  for (int ct = 0; ct < 16; ++ct) O[ct] = {0.f, 0.f, 0.f, 0.f};
  float m_run[4], l_lane[4];
#pragma unroll
  for (int r = 0; r < 4; ++r) { m_run[r] = -1e30f; l_lane[r] = 0.f; }

  const f16* QBp = &sm.u.s.QB[p][0];
  const f16* VBp = &sm.u.s.VB[p][0];

  for (int it = 0; it < 8; ++it) {
    // ---- QK: scores S[16 j][64 i] from LDS, 4 parallel MFMA chains ----
    f32x4 s[4];
#pragma unroll
    for (int f = 0; f < 4; ++f) s[f] = {0.f, 0.f, 0.f, 0.f};
#pragma unroll
    for (int kc = 0; kc < 8; ++kc) {
#pragma unroll
      for (int f = 0; f < 4; ++f) {
        half8 b = *reinterpret_cast<const half8*>(&QBp[(f * 8 + kc) * 512 + lane * 8]);
        s[f] = __builtin_amdgcn_mfma_f32_16x16x32_f16(kf[kc], b, s[f], 0, 0, 0);
      }
    }
    BAR();                                                    // all waves done reading QB
    stage64k8(qbase + (size_t)((it + 1) & 7) * 32768, &sm.u.s.QB[0][0], wave, lane);

    // ---- softmax per j-row over this wave's 64 i (overlaps Q staging) ----
    float alpha[4];
#pragma unroll
    for (int r = 0; r < 4; ++r) {
      float mx = s[0][r];
#pragma unroll
      for (int f = 1; f < 4; ++f) mx = fmaxf(mx, s[f][r]);
#pragma unroll
      for (int off = 1; off < 16; off <<= 1) mx = fmaxf(mx, __shfl_xor(mx, off, 64));
      float mnew = fmaxf(m_run[r], mx);
      alpha[r] = __expf(m_run[r] - mnew);
      m_run[r] = mnew;
      float ps = 0.f;
#pragma unroll
      for (int f = 0; f < 4; ++f) {
        float pv = __expf(s[f][r] - mnew);
        ps += pv;
        sm.P[wave][f >> 1][quad * 4 + r][(f & 1) * 16 + row16] = (f16)pv;
      }
      l_lane[r] = l_lane[r] * alpha[r] + ps;
    }
#pragma unroll
    for (int ct = 0; ct < 16; ++ct)
#pragma unroll
      for (int r = 0; r < 4; ++r) O[ct][r] *= alpha[r];

    VMCNT(8);    // V(it) landed (only next-Q's 8 remain in flight)
    BAR();       // all waves' V(it) visible

    // ---- PV: 2 chunks of 32 i; P same-wave LDS round-trip, vT frags from LDS ----
#pragma unroll
    for (int c4 = 0; c4 < 2; ++c4) {
      half8 pf = *reinterpret_cast<const half8*>(&sm.P[wave][c4][row16][quad * 8]);
#pragma unroll
      for (int ct = 0; ct < 16; ++ct) {
        half8 vf = *reinterpret_cast<const half8*>(&VBp[(c4 * 16 + ct) * 512 + lane * 8]);
        O[ct] = __builtin_amdgcn_mfma_f32_16x16x32_f16(pf, vf, O[ct], 0, 0, 0);
      }
    }
    BAR();                                                    // all waves done reading VB
    stage64k8(vbase + (size_t)((it + 1) & 7) * 32768, &sm.u.s.VB[0][0], wave, lane);
    VMCNT(8);    // Q(it+1) landed (only next-V's 8 remain)
    BAR();
  }
  VMCNT(0);      // drain wrap-around stages before aliasing epilogue over QB/VB
  BAR();

  // ---- pairwise (m, l, O) combine across parity waves ----
#pragma unroll
  for (int r = 0; r < 4; ++r) {
#pragma unroll
    for (int off = 1; off < 16; off <<= 1) l_lane[r] += __shfl_xor(l_lane[r], off, 64);
  }
  if (row16 == 0) {
#pragma unroll
    for (int r = 0; r < 4; ++r) {
      sm.ml[wave][0][quad * 4 + r] = m_run[r];
      sm.ml[wave][1][quad * 4 + r] = l_lane[r];
    }
  }
  BAR();

  int partner = wave ^ 4;
  float alphaS[4], invL[4];
#pragma unroll
  for (int r = 0; r < 4; ++r) {
    int j = quad * 4 + r;
    float ma = m_run[r], mb = sm.ml[partner][0][j];
    float M = fmaxf(ma, mb);
    float la = l_lane[r], lb = sm.ml[partner][1][j];
    float L = la * __expf(ma - M) + lb * __expf(mb - M);
    alphaS[r] = __expf(ma - M);
    invL[r] = 1.f / L;
  }
#pragma unroll
  for (int ct = 0; ct < 16; ++ct)
#pragma unroll
    for (int r = 0; r < 4; ++r) O[ct][r] *= alphaS[r];

  if (p == 1) {
#pragma unroll
    for (int ct = 0; ct < 16; ++ct)
#pragma unroll
      for (int r = 0; r < 4; ++r)
        sm.u.e.a.Ocmb[jt_l][quad * 4 + r][ct * 16 + row16] = O[ct][r];
  }
  BAR();
  if (p == 0) {
#pragma unroll
    for (int ct = 0; ct < 16; ++ct)
#pragma unroll
      for (int r = 0; r < 4; ++r) {
        float v = O[ct][r] + sm.u.e.a.Ocmb[jt_l][quad * 4 + r][ct * 16 + row16];
        sm.u.e.ex[jt_l][quad * 4 + r][ct * 16 + row16] = (f16)(v * invL[r]);
      }
  }
  BAR();   // att tile ready (and Ocmb reads done -> ex2 alias safe)

  // ---- MLP + LN, ct-halves split across the wave pair ----
  half8 af[8];
#pragma unroll
  for (int kc = 0; kc < 8; ++kc)
    af[kc] = *reinterpret_cast<const half8*>(&sm.u.e.ex[jt_l][row16][kc * 32 + quad * 8]);

  // GEMM1: h = silu(att @ w1 + b1) -> ex2 (this wave's 8 ct)
#pragma unroll
  for (int q8 = 0; q8 < 8; ++q8) {
    int ct = p * 8 + q8;
    f32x4 acc = {0.f, 0.f, 0.f, 0.f};
    const f16* brow = w1p + ((size_t)ct * 8) * 512 + lane * 8;
#pragma unroll
    for (int kc = 0; kc < 8; ++kc)
      acc = __builtin_amdgcn_mfma_f32_16x16x32_f16(af[kc], ldg8(brow + kc * 512), acc, 0, 0, 0);
    int co = ct * 16 + row16;
    float bb = b1[co];
#pragma unroll
    for (int r = 0; r < 4; ++r) {
      float xg = acc[r] + bb;
      float hh = xg / (1.f + __expf(-xg));  // SiLU
      sm.u.e.a.ex2[jt_l][quad * 4 + r][co] = (f16)hh;
    }
  }
  BAR();   // full h tile ready

  half8 hf[8];
#pragma unroll
  for (int kc = 0; kc < 8; ++kc)
    hf[kc] = *reinterpret_cast<const half8*>(&sm.u.e.a.ex2[jt_l][row16][kc * 32 + quad * 8]);

  f32x4 acc2[8];
#pragma unroll
  for (int q8 = 0; q8 < 8; ++q8) {
    int ct = p * 8 + q8;
    f32x4 acc = {0.f, 0.f, 0.f, 0.f};
    const f16* brow = w2p + ((size_t)ct * 8) * 512 + lane * 8;
#pragma unroll
    for (int kc = 0; kc < 8; ++kc)
      acc = __builtin_amdgcn_mfma_f32_16x16x32_f16(hf[kc], ldg8(brow + kc * 512), acc, 0, 0, 0);
    float bb = b2[ct * 16 + row16];
#pragma unroll
    for (int r = 0; r < 4; ++r) acc[r] += bb;
    acc2[q8] = acc;
  }

  // LayerNorm over C: per-wave partials (128 channels) + pairwise LDS exchange
  float sum[4] = {0.f, 0.f, 0.f, 0.f}, ssq[4] = {0.f, 0.f, 0.f, 0.f};
#pragma unroll
  for (int q8 = 0; q8 < 8; ++q8)
#pragma unroll
    for (int r = 0; r < 4; ++r) { float xv = acc2[q8][r]; sum[r] += xv; ssq[r] += xv * xv; }
#pragma unroll
  for (int r = 0; r < 4; ++r) {
#pragma unroll
    for (int off = 1; off < 16; off <<= 1) {
      sum[r] += __shfl_xor(sum[r], off, 64);
      ssq[r] += __shfl_xor(ssq[r], off, 64);
    }
  }
  if (row16 == 0) {
#pragma unroll
    for (int r = 0; r < 4; ++r) {
      sm.lnbuf[wave][0][quad * 4 + r] = sum[r];
      sm.lnbuf[wave][1][quad * 4 + r] = ssq[r];
    }
  }
  BAR();

  float mean[4], rstd[4];
#pragma unroll
  for (int r = 0; r < 4; ++r) {
    int j = quad * 4 + r;
    float s = sm.lnbuf[wave][0][j] + sm.lnbuf[partner][0][j];
    float sq = sm.lnbuf[wave][1][j] + sm.lnbuf[partner][1][j];
    mean[r] = s * (1.f / 256.f);
    float var = sq * (1.f / 256.f) - mean[r] * mean[r];
    rstd[r] = rsqrtf(var + 1e-5f);
  }

  // coalesced plain stores: this wave's 128 channels (nontemporal hint removed: R4's
  // WRITE_SIZE was 24 MB with it vs 16.4 expected; R8-R10 plain stores confirmed 16.4)
#pragma unroll
  for (int q8 = 0; q8 < 8; ++q8) {
    int col = (p * 8 + q8) * 16 + row16;
    float g = gamma[col], be = beta[col];
    f32x4 v;
#pragma unroll
    for (int r = 0; r < 4; ++r) v[r] = (acc2[q8][r] - mean[r]) * rstd[r] * g + be;
    *reinterpret_cast<f32x4*>(out + (size_t)(bg * CC + col) * NN + jw + quad * 4) = v;
  }
}

extern "C" void kernel_launch(void* const* d_in, const int* in_sizes, int n_in,
                              void* d_out, int out_size, void* d_ws, size_t ws_size,
                              hipStream_t stream) {
  (void)in_sizes; (void)n_in; (void)out_size;
  const float* x     = (const float*)d_in[0];
  const float* wq    = (const float*)d_in[1];
  const float* bq    = (const float*)d_in[2];
  const float* wk    = (const float*)d_in[3];
  const float* bk    = (const float*)d_in[4];
  const float* wv    = (const float*)d_in[5];
  const float* bv    = (const float*)d_in[6];
  const float* w1    = (const float*)d_in[7];
  const float* b1    = (const float*)d_in[8];
  const float* w2    = (const float*)d_in[9];
  const float* b2    = (const float*)d_in[10];
  const float* gamma = (const float*)d_in[11];
  const float* beta  = (const float*)d_in[12];
  float* out = (float*)d_out;

  const size_t WE = 65536;
  const size_t SB = (size_t)NN * CC;
  f16* base = (f16*)d_ws;
  f16* wqp = base + 0 * WE;
  f16* wkp = base + 1 * WE;
  f16* wvp = base + 2 * WE;
  f16* w1p = base + 3 * WE;
  f16* w2p = base + 4 * WE;

  size_t wbytes = 5 * WE * sizeof(f16);
  size_t perb   = 3 * SB * sizeof(f16);
  int nb = (ws_size > wbytes) ? (int)((ws_size - wbytes) / perb) : 1;
  if (nb < 1) nb = 1;
  if (nb > BB) nb = BB;

  f16* qb  = base + 5 * WE;
  f16* kb  = qb + (size_t)nb * SB;
  f16* vTb = kb + (size_t)nb * SB;

  WP5 p;
  p.s[0] = wq; p.s[1] = wk; p.s[2] = wv; p.s[3] = w1; p.s[4] = w2;
  p.d[0] = wqp; p.d[1] = wkp; p.d[2] = wvp; p.d[3] = w1p; p.d[4] = w2p;
  k_packW<<<dim3(16, 5), 256, 0, stream>>>(p);

  for (int b0 = 0; b0 < BB; b0 += nb) {
    int cb = (b0 + nb <= BB) ? nb : (BB - b0);
    k_qkv<<<dim3(cb, 32, 2), 256, 0, stream>>>(x, wqp, wkp, wvp, bq, bk, bv, qb, kb, vTb, b0);
    k_attn_mlp<<<dim3(cb, 16), 512, 0, stream>>>(qb, kb, vTb, w1p, b1, w2p, b2,
                                                 gamma, beta, out, b0);
  }
}

// Round 12
// 180.008 us; speedup vs baseline: 1.0783x; 1.0181x over previous
//
#include <hip/hip_runtime.h>

#define BB 16
#define CC 256
#define NN 1024

typedef _Float16 f16;
typedef __attribute__((ext_vector_type(8))) _Float16 half8;   // MFMA A/B frag (4 VGPRs)
typedef __attribute__((ext_vector_type(4))) float f32x4;      // MFMA C/D frag

__device__ __forceinline__ half8 ldg8(const f16* p) {
  return *reinterpret_cast<const half8*>(p);
}

// async global->LDS, 16B per lane; lds base must be wave-uniform (HW adds lane*16)
__device__ __forceinline__ void gll16(const f16* g, f16* l) {
  __builtin_amdgcn_global_load_lds((const __attribute__((address_space(1))) void*)g,
                                   (__attribute__((address_space(3))) void*)l, 16, 0, 0);
}

#define VMCNT(n) asm volatile("s_waitcnt vmcnt(" #n ")" ::: "memory")
#define BAR() __builtin_amdgcn_s_barrier()

// stage one contiguous 64 KB chunk with 512 threads (8 waves): 8 issues/thread.
__device__ __forceinline__ void stage64k8(const f16* __restrict__ g, f16* l, int wave, int lane) {
#pragma unroll
  for (int k = 0; k < 8; ++k) {
    int ob = k * 4096 + wave * 512;      // 8 waves x 512 = 4096 per k
    gll16(g + ob + lane * 8, l + ob);
  }
}

// ---------------- weight pack: W fp32 [ci][co] -> frag-packed f16 wp[(ct*8+kc)*512 + lane*8] ----
struct WP5 {
  const float* s[5];
  f16* d[5];
};

__global__ void __launch_bounds__(256) k_packW(WP5 p) {
  __shared__ float ws[256][17];
  int m = blockIdx.y, ct = blockIdx.x;
  const float* W = p.s[m];
  f16* wp = p.d[m];
  int tid = threadIdx.x;
  int col = tid & 15, cig = tid >> 4;
#pragma unroll
  for (int pg = 0; pg < 16; ++pg) {
    int ci = pg * 16 + cig;
    ws[ci][col] = W[(size_t)ci * 256 + ct * 16 + col];
  }
  __syncthreads();
  int lane = tid & 63, wave = tid >> 6;
  int row16 = lane & 15, quad = lane >> 4;
#pragma unroll
  for (int kk = 0; kk < 2; ++kk) {
    int kc = wave * 2 + kk;
    half8 o;
#pragma unroll
    for (int j = 0; j < 8; ++j) o[j] = (f16)ws[kc * 32 + quad * 8 + j][row16];
    *reinterpret_cast<half8*>(wp + ((size_t)ct * 8 + kc) * 512 + lane * 8) = o;
  }
}

// ---------------- QKV, 2-way z-split ----------------
// R12: __launch_bounds__(256, 2). R11 counters exposed qkv's pathology: VGPR_Count=64
// with ~40 MB of scratch-spill writes per dispatch (WRITE 65.5 vs 25 expected), cold
// dispatch 143 us. Launch-bounds model across 4 data points ((512,2)->128, (1024,4)->64,
// (256,4)->64): VGPR budget = 256/arg. arg=2 -> 128 VGPR, fitting the ~95-115 live regs,
// while LDS (33.8 KB x 4) and VGPR (512/128=4 waves/SIMD) still admit 4 blocks/CU.
struct QkvSmem {
  union {
    struct { f16 hi[32][264]; f16 lo[32][264]; } ts;
    f16 ex[2][16][264];
    f16 exv[256][40];
  };
};

__global__ void __launch_bounds__(256, 2) k_qkv(const float* __restrict__ x,
    const f16* __restrict__ wqp, const f16* __restrict__ wkp, const f16* __restrict__ wvp,
    const float* __restrict__ bq, const float* __restrict__ bk, const float* __restrict__ bv,
    f16* __restrict__ qp, f16* __restrict__ kp, f16* __restrict__ vp, int b_base) {
  __shared__ QkvSmem sm;
  int z = blockIdx.z;
  int bl = blockIdx.x, bg = b_base + bl, n0 = blockIdx.y * 32;
  int tid = threadIdx.x, wave = tid >> 6, lane = tid & 63;
  int row16 = lane & 15, quad = lane >> 4;
  int g = wave >> 1, h = wave & 1;

  // ---- load x chunk once; split into hi/lo f16 halves, transposed into LDS ----
#pragma unroll
  for (int e = tid; e < 2048; e += 256) {
    int c = e >> 3, n4 = (e & 7) << 2;
    float4 u = *reinterpret_cast<const float4*>(x + (size_t)(bg * CC + c) * NN + n0 + n4);
    float uv[4] = {u.x, u.y, u.z, u.w};
#pragma unroll
    for (int i = 0; i < 4; ++i) {
      f16 hh = (f16)uv[i];
      sm.ts.hi[n4 + i][c] = hh;
      sm.ts.lo[n4 + i][c] = (f16)(uv[i] - (float)hh);
    }
  }
  __syncthreads();

  half8 ah[8], al[8];
#pragma unroll
  for (int kc = 0; kc < 8; ++kc) {
    ah[kc] = *reinterpret_cast<const half8*>(&sm.ts.hi[g * 16 + row16][kc * 32 + quad * 8]);
    al[kc] = *reinterpret_cast<const half8*>(&sm.ts.lo[g * 16 + row16][kc * 32 + quad * 8]);
  }
  __syncthreads();

  if (z == 0) {
    // ---- q then k: ex reuse is wave-local ----
    const f16* WTs[2]      = {wqp, wkp};
    const float* biases[2] = {bq, bk};
    f16* outs[2]           = {qp, kp};
#pragma unroll
    for (int zz = 0; zz < 2; ++zz) {
      const f16* WT = WTs[zz];
      const float* bias = biases[zz];
      f16* outp = outs[zz];
#pragma unroll
      for (int cp = 0; cp < 2; ++cp) {
#pragma unroll
        for (int uu = 0; uu < 2; ++uu) {
          f32x4 acch[2], accl[2];
#pragma unroll
          for (int u = 0; u < 2; ++u) { acch[u] = {0.f,0.f,0.f,0.f}; accl[u] = {0.f,0.f,0.f,0.f}; }
#pragma unroll
          for (int kc = 0; kc < 8; ++kc) {
#pragma unroll
            for (int u = 0; u < 2; ++u) {
              int ct = h * 8 + cp * 4 + uu * 2 + u;
              half8 b = ldg8(WT + ((size_t)ct * 8 + kc) * 512 + lane * 8);
              acch[u] = __builtin_amdgcn_mfma_f32_16x16x32_f16(ah[kc], b, acch[u], 0, 0, 0);
              accl[u] = __builtin_amdgcn_mfma_f32_16x16x32_f16(al[kc], b, accl[u], 0, 0, 0);
            }
          }
#pragma unroll
          for (int u = 0; u < 2; ++u) {
            int ct = h * 8 + cp * 4 + uu * 2 + u;
            int co = ct * 16 + row16;
            float bb = bias[co];
#pragma unroll
            for (int r = 0; r < 4; ++r)
              sm.ex[g][quad * 4 + r][co] = (f16)(acch[u][r] + accl[u][r] + bb);
          }
        }
      }
      const f16* exr = &sm.ex[g][row16][0];
      size_t fb = ((size_t)bl * 64 + (n0 >> 4) + g) * 8;
#pragma unroll
      for (int k = 0; k < 4; ++k) {
        int kc = h * 4 + k;
        half8 hv = *reinterpret_cast<const half8*>(exr + kc * 32 + quad * 8);
        *reinterpret_cast<half8*>(outp + (fb + kc) * 512 + lane * 8) = hv;
      }
    }
  } else {
    // ---- v: transposed epilogue into exv, then packed vT store ----
#pragma unroll
    for (int cp = 0; cp < 2; ++cp) {
#pragma unroll
      for (int uu = 0; uu < 2; ++uu) {
        f32x4 acch[2], accl[2];
#pragma unroll
        for (int u = 0; u < 2; ++u) { acch[u] = {0.f,0.f,0.f,0.f}; accl[u] = {0.f,0.f,0.f,0.f}; }
#pragma unroll
        for (int kc = 0; kc < 8; ++kc) {
#pragma unroll
          for (int u = 0; u < 2; ++u) {
            int ct = h * 8 + cp * 4 + uu * 2 + u;
            half8 b = ldg8(wvp + ((size_t)ct * 8 + kc) * 512 + lane * 8);
            acch[u] = __builtin_amdgcn_mfma_f32_16x16x32_f16(ah[kc], b, acch[u], 0, 0, 0);
            accl[u] = __builtin_amdgcn_mfma_f32_16x16x32_f16(al[kc], b, accl[u], 0, 0, 0);
          }
        }
#pragma unroll
        for (int u = 0; u < 2; ++u) {
          int ct = h * 8 + cp * 4 + uu * 2 + u;
          int co = ct * 16 + row16;
          float bb = bv[co];
#pragma unroll
          for (int r = 0; r < 4; ++r)
            sm.exv[co][g * 16 + quad * 4 + r] = (f16)(acch[u][r] + accl[u][r] + bb);
        }
      }
    }
    __syncthreads();
    size_t vb = ((size_t)bl * 32 + blockIdx.y) * 16;
#pragma unroll
    for (int f = 0; f < 4; ++f) {
      int ct = wave * 4 + f;
      half8 o = *reinterpret_cast<const half8*>(&sm.exv[ct * 16 + row16][quad * 8]);
      *reinterpret_cast<half8*>(vp + (vb + ct) * 512 + lane * 8) = o;
    }
  }
}

// ---------------- fused flash attention + MLP(SiLU) + LayerNorm (R11, locked) ----------------
// 8 waves = 4 j-tiles x 2 i-parities; per iteration the block stages one 128-i Q chunk +
// V chunk; each parity consumes 64 i with s[4] (8 fat softmax steps — proven optimal
// granularity across R4/R8/R9/R10). Counted vmcnt(8) keeps next chunk in flight.
struct AttnSmem {
  union {
    struct {
      f16 QB[2][64 * 256];   // 2 x 32 KB: packed q frags, chunk parity 0/1
      f16 VB[2][64 * 256];   // 2 x 32 KB: packed vT frags
    } s;
    struct {
      union {
        float Ocmb[4][16][260];   // 66.6 KB: pairwise O-combine (f32)
        f16 ex2[4][16][264];      // 33 KB: MLP hidden h (aliases Ocmb, used after)
      } a;
      f16 ex[4][16][264];         // 33 KB: normalized att per j-tile
    } e;
  } u;                        // 128 KB
  f16 P[8][2][16][40];        // per-wave P round-trip (C->A layout)   20.5 KB
  float ml[8][2][16];         // per-wave {m, l} per j-row              1 KB
  float lnbuf[8][2][16];      // per-wave LN partials {sum, ssq}        1 KB
};

__global__ void __launch_bounds__(512, 2) k_attn_mlp(
    const f16* __restrict__ qp, const f16* __restrict__ kp, const f16* __restrict__ vp,
    const f16* __restrict__ w1p, const float* __restrict__ b1,
    const f16* __restrict__ w2p, const float* __restrict__ b2,
    const float* __restrict__ gamma, const float* __restrict__ beta,
    float* __restrict__ out, int b_base) {
  __shared__ AttnSmem sm;
  int bl = blockIdx.x, bg = b_base + bl;
  int j0 = blockIdx.y * 64;
  int tid = threadIdx.x, wave = tid >> 6, lane = tid & 63;
  int row16 = lane & 15, quad = lane >> 4;
  int jt_l = wave & 3, p = wave >> 2;        // j-tile within block, i-chunk parity
  int jw = j0 + jt_l * 16;

  // A-frags: k rows of this wave's j-tile (partner waves load the same rows; L2-hot)
  const f16* kbase = kp + (size_t)bl * NN * CC;
  int jt = (j0 >> 4) + jt_l;
  half8 kf[8];
#pragma unroll
  for (int kc = 0; kc < 8; ++kc)
    kf[kc] = ldg8(kbase + ((size_t)jt * 8 + kc) * 512 + lane * 8);

  const f16* qbase = qp + (size_t)bl * NN * CC;
  const f16* vbase = vp + (size_t)bl * CC * NN;

  // prologue: stage chunk pair 0 (chunks 0,1 = 64 KB) of Q and V
  stage64k8(qbase, &sm.u.s.QB[0][0], wave, lane);
  stage64k8(vbase, &sm.u.s.VB[0][0], wave, lane);
  VMCNT(8);   // kf(8) + Q(8) drained, V(8) in flight
  BAR();

  f32x4 O[16];
#pragma unroll
  for (int ct = 0; ct < 16; ++ct) O[ct] = {0.f, 0.f, 0.f, 0.f};
  float m_run[4], l_lane[4];
#pragma unroll
  for (int r = 0; r < 4; ++r) { m_run[r] = -1e30f; l_lane[r] = 0.f; }

  const f16* QBp = &sm.u.s.QB[p][0];
  const f16* VBp = &sm.u.s.VB[p][0];

  for (int it = 0; it < 8; ++it) {
    // ---- QK: scores S[16 j][64 i] from LDS, 4 parallel MFMA chains ----
    f32x4 s[4];
#pragma unroll
    for (int f = 0; f < 4; ++f) s[f] = {0.f, 0.f, 0.f, 0.f};
#pragma unroll
    for (int kc = 0; kc < 8; ++kc) {
#pragma unroll
      for (int f = 0; f < 4; ++f) {
        half8 b = *reinterpret_cast<const half8*>(&QBp[(f * 8 + kc) * 512 + lane * 8]);
        s[f] = __builtin_amdgcn_mfma_f32_16x16x32_f16(kf[kc], b, s[f], 0, 0, 0);
      }
    }
    BAR();                                                    // all waves done reading QB
    stage64k8(qbase + (size_t)((it + 1) & 7) * 32768, &sm.u.s.QB[0][0], wave, lane);

    // ---- softmax per j-row over this wave's 64 i (overlaps Q staging) ----
    float alpha[4];
#pragma unroll
    for (int r = 0; r < 4; ++r) {
      float mx = s[0][r];
#pragma unroll
      for (int f = 1; f < 4; ++f) mx = fmaxf(mx, s[f][r]);
#pragma unroll
      for (int off = 1; off < 16; off <<= 1) mx = fmaxf(mx, __shfl_xor(mx, off, 64));
      float mnew = fmaxf(m_run[r], mx);
      alpha[r] = __expf(m_run[r] - mnew);
      m_run[r] = mnew;
      float ps = 0.f;
#pragma unroll
      for (int f = 0; f < 4; ++f) {
        float pv = __expf(s[f][r] - mnew);
        ps += pv;
        sm.P[wave][f >> 1][quad * 4 + r][(f & 1) * 16 + row16] = (f16)pv;
      }
      l_lane[r] = l_lane[r] * alpha[r] + ps;
    }
#pragma unroll
    for (int ct = 0; ct < 16; ++ct)
#pragma unroll
      for (int r = 0; r < 4; ++r) O[ct][r] *= alpha[r];

    VMCNT(8);    // V(it) landed (only next-Q's 8 remain in flight)
    BAR();       // all waves' V(it) visible

    // ---- PV: 2 chunks of 32 i; P same-wave LDS round-trip, vT frags from LDS ----
#pragma unroll
    for (int c4 = 0; c4 < 2; ++c4) {
      half8 pf = *reinterpret_cast<const half8*>(&sm.P[wave][c4][row16][quad * 8]);
#pragma unroll
      for (int ct = 0; ct < 16; ++ct) {
        half8 vf = *reinterpret_cast<const half8*>(&VBp[(c4 * 16 + ct) * 512 + lane * 8]);
        O[ct] = __builtin_amdgcn_mfma_f32_16x16x32_f16(pf, vf, O[ct], 0, 0, 0);
      }
    }
    BAR();                                                    // all waves done reading VB
    stage64k8(vbase + (size_t)((it + 1) & 7) * 32768, &sm.u.s.VB[0][0], wave, lane);
    VMCNT(8);    // Q(it+1) landed (only next-V's 8 remain)
    BAR();
  }
  VMCNT(0);      // drain wrap-around stages before aliasing epilogue over QB/VB
  BAR();

  // ---- pairwise (m, l, O) combine across parity waves ----
#pragma unroll
  for (int r = 0; r < 4; ++r) {
#pragma unroll
    for (int off = 1; off < 16; off <<= 1) l_lane[r] += __shfl_xor(l_lane[r], off, 64);
  }
  if (row16 == 0) {
#pragma unroll
    for (int r = 0; r < 4; ++r) {
      sm.ml[wave][0][quad * 4 + r] = m_run[r];
      sm.ml[wave][1][quad * 4 + r] = l_lane[r];
    }
  }
  BAR();

  int partner = wave ^ 4;
  float alphaS[4], invL[4];
#pragma unroll
  for (int r = 0; r < 4; ++r) {
    int j = quad * 4 + r;
    float ma = m_run[r], mb = sm.ml[partner][0][j];
    float M = fmaxf(ma, mb);
    float la = l_lane[r], lb = sm.ml[partner][1][j];
    float L = la * __expf(ma - M) + lb * __expf(mb - M);
    alphaS[r] = __expf(ma - M);
    invL[r] = 1.f / L;
  }
#pragma unroll
  for (int ct = 0; ct < 16; ++ct)
#pragma unroll
    for (int r = 0; r < 4; ++r) O[ct][r] *= alphaS[r];

  if (p == 1) {
#pragma unroll
    for (int ct = 0; ct < 16; ++ct)
#pragma unroll
      for (int r = 0; r < 4; ++r)
        sm.u.e.a.Ocmb[jt_l][quad * 4 + r][ct * 16 + row16] = O[ct][r];
  }
  BAR();
  if (p == 0) {
#pragma unroll
    for (int ct = 0; ct < 16; ++ct)
#pragma unroll
      for (int r = 0; r < 4; ++r) {
        float v = O[ct][r] + sm.u.e.a.Ocmb[jt_l][quad * 4 + r][ct * 16 + row16];
        sm.u.e.ex[jt_l][quad * 4 + r][ct * 16 + row16] = (f16)(v * invL[r]);
      }
  }
  BAR();   // att tile ready (and Ocmb reads done -> ex2 alias safe)

  // ---- MLP + LN, ct-halves split across the wave pair ----
  half8 af[8];
#pragma unroll
  for (int kc = 0; kc < 8; ++kc)
    af[kc] = *reinterpret_cast<const half8*>(&sm.u.e.ex[jt_l][row16][kc * 32 + quad * 8]);

  // GEMM1: h = silu(att @ w1 + b1) -> ex2 (this wave's 8 ct)
#pragma unroll
  for (int q8 = 0; q8 < 8; ++q8) {
    int ct = p * 8 + q8;
    f32x4 acc = {0.f, 0.f, 0.f, 0.f};
    const f16* brow = w1p + ((size_t)ct * 8) * 512 + lane * 8;
#pragma unroll
    for (int kc = 0; kc < 8; ++kc)
      acc = __builtin_amdgcn_mfma_f32_16x16x32_f16(af[kc], ldg8(brow + kc * 512), acc, 0, 0, 0);
    int co = ct * 16 + row16;
    float bb = b1[co];
#pragma unroll
    for (int r = 0; r < 4; ++r) {
      float xg = acc[r] + bb;
      float hh = xg / (1.f + __expf(-xg));  // SiLU
      sm.u.e.a.ex2[jt_l][quad * 4 + r][co] = (f16)hh;
    }
  }
  BAR();   // full h tile ready

  half8 hf[8];
#pragma unroll
  for (int kc = 0; kc < 8; ++kc)
    hf[kc] = *reinterpret_cast<const half8*>(&sm.u.e.a.ex2[jt_l][row16][kc * 32 + quad * 8]);

  f32x4 acc2[8];
#pragma unroll
  for (int q8 = 0; q8 < 8; ++q8) {
    int ct = p * 8 + q8;
    f32x4 acc = {0.f, 0.f, 0.f, 0.f};
    const f16* brow = w2p + ((size_t)ct * 8) * 512 + lane * 8;
#pragma unroll
    for (int kc = 0; kc < 8; ++kc)
      acc = __builtin_amdgcn_mfma_f32_16x16x32_f16(hf[kc], ldg8(brow + kc * 512), acc, 0, 0, 0);
    float bb = b2[ct * 16 + row16];
#pragma unroll
    for (int r = 0; r < 4; ++r) acc[r] += bb;
    acc2[q8] = acc;
  }

  // LayerNorm over C: per-wave partials (128 channels) + pairwise LDS exchange
  float sum[4] = {0.f, 0.f, 0.f, 0.f}, ssq[4] = {0.f, 0.f, 0.f, 0.f};
#pragma unroll
  for (int q8 = 0; q8 < 8; ++q8)
#pragma unroll
    for (int r = 0; r < 4; ++r) { float xv = acc2[q8][r]; sum[r] += xv; ssq[r] += xv * xv; }
#pragma unroll
  for (int r = 0; r < 4; ++r) {
#pragma unroll
    for (int off = 1; off < 16; off <<= 1) {
      sum[r] += __shfl_xor(sum[r], off, 64);
      ssq[r] += __shfl_xor(ssq[r], off, 64);
    }
  }
  if (row16 == 0) {
#pragma unroll
    for (int r = 0; r < 4; ++r) {
      sm.lnbuf[wave][0][quad * 4 + r] = sum[r];
      sm.lnbuf[wave][1][quad * 4 + r] = ssq[r];
    }
  }
  BAR();

  float mean[4], rstd[4];
#pragma unroll
  for (int r = 0; r < 4; ++r) {
    int j = quad * 4 + r;
    float s = sm.lnbuf[wave][0][j] + sm.lnbuf[partner][0][j];
    float sq = sm.lnbuf[wave][1][j] + sm.lnbuf[partner][1][j];
    mean[r] = s * (1.f / 256.f);
    float var = sq * (1.f / 256.f) - mean[r] * mean[r];
    rstd[r] = rsqrtf(var + 1e-5f);
  }

  // coalesced plain stores: this wave's 128 channels
#pragma unroll
  for (int q8 = 0; q8 < 8; ++q8) {
    int col = (p * 8 + q8) * 16 + row16;
    float g = gamma[col], be = beta[col];
    f32x4 v;
#pragma unroll
    for (int r = 0; r < 4; ++r) v[r] = (acc2[q8][r] - mean[r]) * rstd[r] * g + be;
    *reinterpret_cast<f32x4*>(out + (size_t)(bg * CC + col) * NN + jw + quad * 4) = v;
  }
}

extern "C" void kernel_launch(void* const* d_in, const int* in_sizes, int n_in,
                              void* d_out, int out_size, void* d_ws, size_t ws_size,
                              hipStream_t stream) {
  (void)in_sizes; (void)n_in; (void)out_size;
  const float* x     = (const float*)d_in[0];
  const float* wq    = (const float*)d_in[1];
  const float* bq    = (const float*)d_in[2];
  const float* wk    = (const float*)d_in[3];
  const float* bk    = (const float*)d_in[4];
  const float* wv    = (const float*)d_in[5];
  const float* bv    = (const float*)d_in[6];
  const float* w1    = (const float*)d_in[7];
  const float* b1    = (const float*)d_in[8];
  const float* w2    = (const float*)d_in[9];
  const float* b2    = (const float*)d_in[10];
  const float* gamma = (const float*)d_in[11];
  const float* beta  = (const float*)d_in[12];
  float* out = (float*)d_out;

  const size_t WE = 65536;
  const size_t SB = (size_t)NN * CC;
  f16* base = (f16*)d_ws;
  f16* wqp = base + 0 * WE;
  f16* wkp = base + 1 * WE;
  f16* wvp = base + 2 * WE;
  f16* w1p = base + 3 * WE;
  f16* w2p = base + 4 * WE;

  size_t wbytes = 5 * WE * sizeof(f16);
  size_t perb   = 3 * SB * sizeof(f16);
  int nb = (ws_size > wbytes) ? (int)((ws_size - wbytes) / perb) : 1;
  if (nb < 1) nb = 1;
  if (nb > BB) nb = BB;

  f16* qb  = base + 5 * WE;
  f16* kb  = qb + (size_t)nb * SB;
  f16* vTb = kb + (size_t)nb * SB;

  WP5 p;
  p.s[0] = wq; p.s[1] = wk; p.s[2] = wv; p.s[3] = w1; p.s[4] = w2;
  p.d[0] = wqp; p.d[1] = wkp; p.d[2] = wvp; p.d[3] = w1p; p.d[4] = w2p;
  k_packW<<<dim3(16, 5), 256, 0, stream>>>(p);

  for (int b0 = 0; b0 < BB; b0 += nb) {
    int cb = (b0 + nb <= BB) ? nb : (BB - b0);
    k_qkv<<<dim3(cb, 32, 2), 256, 0, stream>>>(x, wqp, wkp, wvp, bq, bk, bv, qb, kb, vTb, b0);
    k_attn_mlp<<<dim3(cb, 16), 512, 0, stream>>>(qb, kb, vTb, w1p, b1, w2p, b2,
                                                 gamma, beta, out, b0);
  }
}